// Round 2
// baseline (1155.933 us; speedup 1.0000x reference)
//
#include <hip/hip_runtime.h>

// ---------------- problem constants ----------------
#define HID    1152
#define SEMD   256
#define STDD   8
#define DDIM   384
#define MUNITS 16
#define INDIM  1420
#define KPAD   1440     // 45*32, zero-padded
#define NSTEPS 45
#define BB     8
#define TT     64
#define KKT    128
#define NTOK   65536    // BB*TT*KKT
#define ASG_OFF  25165824   // NTOK*DDIM
#define UNI_OFF  26214400   // ASG_OFF + NTOK*MUNITS

typedef _Float16 f16;
typedef _Float16 f16x2 __attribute__((ext_vector_type(2)));
typedef _Float16 f16x4 __attribute__((ext_vector_type(4)));
typedef _Float16 f16x8 __attribute__((ext_vector_type(8)));
typedef float    f32x2 __attribute__((ext_vector_type(2)));
typedef float    f32x4 __attribute__((ext_vector_type(4)));

#define MFMA16(A,B,C) __builtin_amdgcn_mfma_f32_16x16x32_f16((A),(B),(C),0,0,0)

// fp32 -> f16 hi + scaled-lo split. lo is scaled by 2^12 so it stays in
// f16 normal range (avoids MFMA subnormal-flush hazards); the cross-product
// accumulator is multiplied by 2^-12 at the epilogue. Residual error ~2^-22
// relative (missing lo*lo term) -- below fp32 dot-product reorder noise.
__device__ __forceinline__ void fsplit(float v, f16 &h, f16 &l){
  f16 hh = (f16)v;
  h = hh;
  l = (f16)((v - (float)hh) * 4096.0f);
}

// ---------------- k_zero ----------------
__global__ void k_zero(float* __restrict__ p, int n){
  int i = blockIdx.x*256 + threadIdx.x;
  if (i < n) p[i] = 0.0f;
}

// ---------------- k_prep ----------------
// Builds W_in transposed+split into per-(8k-chunk) layout:
//   wt[(k>>3)*384*8 + n*8 + (k&7)]  (so LDS staging is a linear copy)
// and broadcasts unit_queries into units_cur[b][m][d].
__global__ void k_prep(const float* __restrict__ W_in, const float* __restrict__ uq,
                       f16* __restrict__ wt_hi, f16* __restrict__ wt_lo,
                       float* __restrict__ units_cur){
  const int tid = blockIdx.x*256 + threadIdx.x;
  const int nthr = gridDim.x*256;
  for (int i = tid; i < KPAD*DDIM; i += nthr){
    const int k = i / DDIM;
    const int n = i - k*DDIM;
    float v = (k < INDIM) ? W_in[i] : 0.0f;   // W_in row-major: i = k*384+n
    f16 h, l; fsplit(v, h, l);
    const int addr = (k>>3)*(DDIM*8) + n*8 + (k&7);
    wt_hi[addr] = h; wt_lo[addr] = l;
  }
  for (int i = tid; i < BB*MUNITS*DDIM; i += nthr){
    units_cur[i] = uq[i % (MUNITS*DDIM)];
  }
}

// ---------------- k_gemm ----------------
// tf = concat(backbone, sem, state, priors) @ W_in + b_in
// 128 tokens x 128 cols per block, BK=32, 45 K-steps, double-buffered LDS.
// fp32 emulated via f16 split: acc1 += Ah*Bh ; acc2 += Ah*Bl' + Al'*Bh.
__global__ __launch_bounds__(256, 2)
void k_gemm(const float* __restrict__ bb, const float* __restrict__ state,
            const float* __restrict__ semt, const float* __restrict__ obj,
            const float* __restrict__ inst, const f16* __restrict__ wt_hi,
            const f16* __restrict__ wt_lo, const float* __restrict__ b_in,
            float* __restrict__ tf_out){
  __shared__ f16 A_hi[2][4096];   // [buf][c(4)][row(128)][8]
  __shared__ f16 A_lo[2][4096];
  __shared__ f16 B_hi[2][4096];   // [buf][c(4)][nrow(128)][8]
  __shared__ f16 B_lo[2][4096];

  const int tid = threadIdx.x;
  const int bid = blockIdx.x;
  const int tokTile = bid / 3;
  const int nTile   = bid - tokTile*3;
  const int tok0 = tokTile*128;   // 128 consecutive tokens: fixed (b,t), kk=row
  const int n0   = nTile*128;
  const int b    = tok0 >> 13;
  const int t    = (tok0 >> 7) & 63;
  const float tn = (float)t * (1.0f/63.0f);

  auto stageA = [&](int step, int bufsel){
    const int kq = tid & 7;       // which float4 within the 32-wide k-step
    const int rbase = tid >> 3;
    #pragma unroll
    for (int i = 0; i < 4; ++i){
      const int row = rbase + i*32;
      f32x4 v;
      if (step < 36){
        v = *(const f32x4*)(bb + (size_t)(tok0+row)*HID + step*32 + kq*4);
      } else if (step < 44){
        v = *(const f32x4*)(semt + (size_t)(b*KKT+row)*SEMD + (step-36)*32 + kq*4);
      } else if (kq < 2){
        v = *(const f32x4*)(state + (size_t)(tok0+row)*STDD + kq*4);
      } else if (kq == 2){
        v[0] = obj[b*KKT + row];                       // objectness
        v[1] = inst[(size_t)(b*KKT + row)*TT + t];     // instance_valid[b,k,t]
        v[2] = tn;
        v[3] = 1.0f - tn;
      } else {
        v[0]=0.f; v[1]=0.f; v[2]=0.f; v[3]=0.f;        // K padding 1420..1439
      }
      f16x4 h, l;
      #pragma unroll
      for (int j = 0; j < 4; ++j){ f16 hh, ll; fsplit(v[j], hh, ll); h[j]=hh; l[j]=ll; }
      const int off = ((kq>>1)*128 + row)*8 + (kq&1)*4;
      *(f16x4*)&A_hi[bufsel][off] = h;
      *(f16x4*)&A_lo[bufsel][off] = l;
    }
  };
  auto stageB = [&](int step, int bufsel){
    #pragma unroll
    for (int q = 0; q < 2; ++q){
      const int idx = tid + q*256;  // c = idx>>7, nrow = idx&127 ; linear copy
      const size_t src = (size_t)(step*4 + (idx>>7))*(DDIM*8) + (size_t)(n0 + (idx&127))*8;
      *(f16x8*)&B_hi[bufsel][idx*8] = *(const f16x8*)(wt_hi + src);
      *(f16x8*)&B_lo[bufsel][idx*8] = *(const f16x8*)(wt_lo + src);
    }
  };

  stageA(0, 0);
  stageB(0, 0);
  __syncthreads();

  const int lane = tid & 63;
  const int w    = tid >> 6;
  const int r16  = lane & 15;
  const int kc   = lane >> 4;
  const int wm   = (w >> 1)*64;
  const int wn   = (w & 1)*64;

  f32x4 acc1[4][4], acc2[4][4];
  #pragma unroll
  for (int m=0;m<4;++m){
    #pragma unroll
    for (int n=0;n<4;++n){
      f32x4 z = {0.f,0.f,0.f,0.f};
      acc1[m][n] = z; acc2[m][n] = z;
    }
  }

  for (int step = 0; step < NSTEPS; ++step){
    const int buf = step & 1;
    if (step < NSTEPS-1){ stageA(step+1, buf^1); stageB(step+1, buf^1); }
    const f16x8* pAh = (const f16x8*)A_hi[buf];
    const f16x8* pAl = (const f16x8*)A_lo[buf];
    const f16x8* pBh = (const f16x8*)B_hi[buf];
    const f16x8* pBl = (const f16x8*)B_lo[buf];
    f16x8 bhv[4], blv[4];
    #pragma unroll
    for (int n=0;n<4;++n){
      const int bi = kc*128 + wn + n*16 + r16;
      bhv[n] = pBh[bi]; blv[n] = pBl[bi];
    }
    #pragma unroll
    for (int m=0;m<4;++m){
      const int ai = kc*128 + wm + m*16 + r16;
      const f16x8 ah = pAh[ai];
      const f16x8 al = pAl[ai];
      #pragma unroll
      for (int n=0;n<4;++n){
        acc1[m][n] = MFMA16(ah, bhv[n], acc1[m][n]);
        acc2[m][n] = MFMA16(ah, blv[n], acc2[m][n]);
        acc2[m][n] = MFMA16(al, bhv[n], acc2[m][n]);
      }
    }
    __syncthreads();
  }

  #pragma unroll
  for (int n=0;n<4;++n){
    const int col = n0 + wn + n*16 + r16;
    const float bias = b_in[col];
    #pragma unroll
    for (int m=0;m<4;++m){
      #pragma unroll
      for (int j=0;j<4;++j){
        const int row = tok0 + wm + m*16 + kc*4 + j;   // C: row=(lane>>4)*4+reg
        tf_out[(size_t)row*DDIM + col] = acc1[m][n][j] + acc2[m][n][j]*(1.0f/4096.0f) + bias;
      }
    }
  }
}

// ---------------- k_assign ----------------
// logits = tf @ units^T * scale (bias cancels in top-k AND softmax),
// top-2 per token, exact 2-entry softmax / TEMP, token_valid zeroing,
// writes assignment and accumulates denom.
__global__ void k_assign(const float* __restrict__ tf, const float* __restrict__ units_src,
                         int bstride, const int* __restrict__ mask,
                         float* __restrict__ asg, float* __restrict__ denom_ws){
  __shared__ f16 U_hi[MUNITS*48*8];     // [m][chunk^((m&7))][8]  (XOR bank swizzle)
  __shared__ f16 U_lo[MUNITS*48*8];
  __shared__ float denom_lds[MUNITS];

  const int tid = threadIdx.x;
  const int tok0 = blockIdx.x * 256;
  const int b = tok0 >> 13;

  { // stage + split units for this batch
    const int mu = tid >> 4;
    const int seg = tid & 15;
    const float* src = units_src + (size_t)b*bstride + mu*DDIM;
    #pragma unroll
    for (int c3 = 0; c3 < 3; ++c3){
      const int kchunk = seg*3 + c3;
      const f32x4 x0 = *(const f32x4*)(src + kchunk*8);
      const f32x4 x1 = *(const f32x4*)(src + kchunk*8 + 4);
      f16x8 h, l;
      #pragma unroll
      for (int j=0;j<4;++j){ f16 hh,ll; fsplit(x0[j],hh,ll); h[j]=hh;   l[j]=ll; }
      #pragma unroll
      for (int j=0;j<4;++j){ f16 hh,ll; fsplit(x1[j],hh,ll); h[4+j]=hh; l[4+j]=ll; }
      const int off = (mu*48 + (kchunk ^ (mu&7)))*8;
      *(f16x8*)&U_hi[off] = h;
      *(f16x8*)&U_lo[off] = l;
    }
  }
  if (tid < MUNITS) denom_lds[tid] = 0.0f;
  __syncthreads();

  const int lane = tid & 63;
  const int w = tid >> 6;
  const int r16 = lane & 15;
  const int kc = lane >> 4;
  const int tw = tok0 + w*64;     // 64 tokens per wave
  const int maskbase = b*KKT;
  float dsum = 0.0f;

  #pragma unroll 1
  for (int mf = 0; mf < 4; ++mf){
    f32x4 l1 = {0.f,0.f,0.f,0.f};
    f32x4 l2 = {0.f,0.f,0.f,0.f};
    const float* tfrow = tf + (size_t)(tw + mf*16 + r16)*DDIM + kc*8;
    #pragma unroll
    for (int step = 0; step < 12; ++step){
      const f32x4 x0 = *(const f32x4*)(tfrow + step*32);
      const f32x4 x1 = *(const f32x4*)(tfrow + step*32 + 4);
      f16x8 ah, al;
      #pragma unroll
      for (int j=0;j<4;++j){ f16 hh,ll; fsplit(x0[j],hh,ll); ah[j]=hh;   al[j]=ll; }
      #pragma unroll
      for (int j=0;j<4;++j){ f16 hh,ll; fsplit(x1[j],hh,ll); ah[4+j]=hh; al[4+j]=ll; }
      const int ui = (r16*48 + ((step*4 + kc) ^ (r16&7)))*8;
      const f16x8 bh = *(const f16x8*)&U_hi[ui];
      const f16x8 bl = *(const f16x8*)&U_lo[ui];
      l1 = MFMA16(ah, bh, l1);
      l2 = MFMA16(ah, bl, l2);
      l2 = MFMA16(al, bh, l2);
    }
    #pragma unroll
    for (int j = 0; j < 4; ++j){
      const float v = (l1[j] + l2[j]*(1.0f/4096.0f)) * 0.051031036307982876f; // 1/sqrt(384)
      const int tokr = tw + mf*16 + kc*4 + j;
      // top-1 over the 16 lanes of this group (m dim), ties -> lower index
      float vmax = v; int imax = r16;
      #pragma unroll
      for (int s=1;s<16;s<<=1){
        const float ov = __shfl_xor(vmax, s, 16);
        const int   oi = __shfl_xor(imax, s, 16);
        if (ov > vmax || (ov == vmax && oi < imax)){ vmax = ov; imax = oi; }
      }
      // top-2 (exclude imax)
      float v2 = (r16 == imax) ? -3.0e38f : v;
      int   i2 = (r16 == imax) ? 127 : r16;
      #pragma unroll
      for (int s=1;s<16;s<<=1){
        const float ov = __shfl_xor(v2, s, 16);
        const int   oi = __shfl_xor(i2, s, 16);
        if (ov > v2 || (ov == v2 && oi < i2)){ v2 = ov; i2 = oi; }
      }
      const float e = expf((v2 - vmax) / 0.7f);   // masked non-top2 -> exp(-inf)=0 exactly
      const float a1 = 1.0f/(1.0f + e);
      const float a2 = e/(1.0f + e);
      const bool valid = mask[maskbase + (tokr & 127)] != 0;
      float myv = 0.0f;
      if (valid){
        if (r16 == imax) myv = a1;
        else if (r16 == i2) myv = a2;
      }
      asg[(size_t)tokr*MUNITS + r16] = myv;
      dsum += myv;
    }
  }
  atomicAdd(&denom_lds[r16], dsum);
  __syncthreads();
  if (tid < MUNITS) atomicAdd(&denom_ws[b*MUNITS + tid], denom_lds[tid]);
}

// ---------------- k_updates ----------------
// updates[b][m][d] = sum_tok assignment[tok][m] * tf[tok][d]
// MFMA: A = assignment^T (M=16), B = tf (K=tokens, N=384), f16-split x3.
// Each block: one batch, 256-token K-chunk, atomicAdd into updates_ws.
__global__ void k_updates(const float* __restrict__ tf, const float* __restrict__ asg,
                          float* __restrict__ upd_ws){
  __shared__ f16 Bt_hi[DDIM*40];   // [d][tok(32) + pad8]  (stride 40 f16: aligned + bank-safe)
  __shared__ f16 Bt_lo[DDIM*40];
  __shared__ f16 At_hi[512];       // [c(4)][m(16)][8]
  __shared__ f16 At_lo[512];

  const int tid = threadIdx.x;
  const int b = blockIdx.x >> 5;
  const int chunk = blockIdx.x & 31;
  const int tokB = b*8192 + chunk*256;

  const int lane = tid & 63;
  const int w = tid >> 6;
  const int r16 = lane & 15;
  const int kc = lane >> 4;
  const int dbase = w*96;          // wave covers 96 of 384 cols

  const int p = tid & 15;          // token pair
  const int dseg = tid >> 4;       // 16 segs x 24 d

  f32x4 acc1[6], acc2[6];
  #pragma unroll
  for (int n=0;n<6;++n){ f32x4 z={0.f,0.f,0.f,0.f}; acc1[n]=z; acc2[n]=z; }

  for (int step = 0; step < 8; ++step){
    const int tok0s = tokB + step*32;
    { // stage tf -> Bt (transpose + split); two tokens per thread -> b32 writes
      const size_t r0 = (size_t)(tok0s + 2*p)*DDIM;
      const size_t r1 = r0 + DDIM;
      #pragma unroll
      for (int q = 0; q < 6; ++q){
        const f32x4 xa = *(const f32x4*)(tf + r0 + dseg*24 + q*4);
        const f32x4 xb = *(const f32x4*)(tf + r1 + dseg*24 + q*4);
        #pragma unroll
        for (int j = 0; j < 4; ++j){
          const int d = dseg*24 + q*4 + j;
          f16 ha, la, hb, lb;
          fsplit(xa[j], ha, la);
          fsplit(xb[j], hb, lb);
          f16x2 hh = {ha, hb};
          f16x2 ll = {la, lb};
          *(f16x2*)&Bt_hi[d*40 + 2*p] = hh;
          *(f16x2*)&Bt_lo[d*40 + 2*p] = ll;
        }
      }
    }
    { // stage assignment -> At (transpose + split)
      const int idx = tid*2;
      const int tokr = idx >> 4;
      const int m2 = idx & 15;
      const f32x2 av = *(const f32x2*)(asg + (size_t)(tok0s + tokr)*MUNITS + m2);
      #pragma unroll
      for (int j = 0; j < 2; ++j){
        f16 h, l; fsplit(av[j], h, l);
        const int off = ((tokr>>3)*16 + m2 + j)*8 + (tokr&7);
        At_hi[off] = h; At_lo[off] = l;
      }
    }
    __syncthreads();
    const f16x8 ah = *(const f16x8*)&At_hi[(kc*16 + r16)*8];
    const f16x8 al = *(const f16x8*)&At_lo[(kc*16 + r16)*8];
    #pragma unroll
    for (int n = 0; n < 6; ++n){
      const int d = dbase + n*16 + r16;
      const f16x8 bh = *(const f16x8*)&Bt_hi[d*40 + kc*8];
      const f16x8 bl = *(const f16x8*)&Bt_lo[d*40 + kc*8];
      acc1[n] = MFMA16(ah, bh, acc1[n]);
      acc2[n] = MFMA16(ah, bl, acc2[n]);
      acc2[n] = MFMA16(al, bh, acc2[n]);
    }
    __syncthreads();
  }

  #pragma unroll
  for (int n = 0; n < 6; ++n){
    #pragma unroll
    for (int j = 0; j < 4; ++j){
      const int m = kc*4 + j;
      const int d = dbase + n*16 + r16;
      atomicAdd(&upd_ws[(size_t)(b*MUNITS + m)*DDIM + d],
                acc1[n][j] + acc2[n][j]*(1.0f/4096.0f));
    }
  }
}

// ---------------- k_units ----------------
// One block (384 threads) per (b,m): updates/denom -> LN -> GELU-MLP -> residual LN.
__global__ void k_units(const float* __restrict__ upd_ws, const float* __restrict__ denom_ws,
                        const float* __restrict__ units_in, int bstride,
                        const float* __restrict__ W1, const float* __restrict__ b1v,
                        const float* __restrict__ W2, const float* __restrict__ b2v,
                        const float* __restrict__ ug, const float* __restrict__ ubv,
                        const float* __restrict__ ng, const float* __restrict__ nbv,
                        float* __restrict__ units_out, float* __restrict__ final_out){
  const int bm = blockIdx.x;
  const int bq = bm >> 4, mq = bm & 15;
  const int tid = threadIdx.x;    // 384
  __shared__ float uln[DDIM];
  __shared__ float gact[2*DDIM];
  __shared__ float red[6];

  float dnm = denom_ws[bm];
  if (dnm < 1e-6f) dnm = 1e-6f;
  float u = upd_ws[(size_t)bm*DDIM + tid] / dnm;

  float s = u;
  #pragma unroll
  for (int sh=1; sh<64; sh<<=1) s += __shfl_xor(s, sh, 64);
  if ((tid&63)==0) red[tid>>6] = s;
  __syncthreads();
  const float mu = (red[0]+red[1]+red[2]+red[3]+red[4]+red[5]) * (1.0f/384.0f);
  __syncthreads();
  const float d = u - mu;
  float s2 = d*d;
  #pragma unroll
  for (int sh=1; sh<64; sh<<=1) s2 += __shfl_xor(s2, sh, 64);
  if ((tid&63)==0) red[tid>>6] = s2;
  __syncthreads();
  const float var = (red[0]+red[1]+red[2]+red[3]+red[4]+red[5]) * (1.0f/384.0f);
  const float rs = rsqrtf(var + 1e-5f);
  uln[tid] = d * rs * ug[tid] + ubv[tid];
  __syncthreads();

  { // h1 = uln @ W1 + b1 ; exact GELU
    float a0 = 0.f, a1 = 0.f;
    for (int dd = 0; dd < DDIM; ++dd){
      const float x = uln[dd];
      a0 += x * W1[(size_t)dd*768 + tid];
      a1 += x * W1[(size_t)dd*768 + tid + 384];
    }
    a0 += b1v[tid]; a1 += b1v[tid + 384];
    gact[tid]     = 0.5f*a0*(1.0f + erff(a0*0.70710678118654752f));
    gact[tid+384] = 0.5f*a1*(1.0f + erff(a1*0.70710678118654752f));
  }
  __syncthreads();

  float h2 = 0.f;
  for (int dd = 0; dd < 2*DDIM; ++dd){
    h2 += gact[dd] * W2[(size_t)dd*DDIM + tid];
  }
  h2 += b2v[tid];
  const float r = units_in[(size_t)bq*bstride + mq*DDIM + tid] + h2;

  float sr = r;
  #pragma unroll
  for (int sh=1; sh<64; sh<<=1) sr += __shfl_xor(sr, sh, 64);
  if ((tid&63)==0) red[tid>>6] = sr;
  __syncthreads();
  const float mu2 = (red[0]+red[1]+red[2]+red[3]+red[4]+red[5]) * (1.0f/384.0f);
  __syncthreads();
  const float d2 = r - mu2;
  float sq2 = d2*d2;
  #pragma unroll
  for (int sh=1; sh<64; sh<<=1) sq2 += __shfl_xor(sq2, sh, 64);
  if ((tid&63)==0) red[tid>>6] = sq2;
  __syncthreads();
  const float var2 = (red[0]+red[1]+red[2]+red[3]+red[4]+red[5]) * (1.0f/384.0f);
  const float rs2 = rsqrtf(var2 + 1e-5f);
  const float outv = d2 * rs2 * ng[tid] + nbv[tid];
  units_out[(size_t)bm*DDIM + tid] = outv;
  if (final_out) final_out[(size_t)bm*DDIM + tid] = outv;
}

// ---------------- launch ----------------
extern "C" void kernel_launch(void* const* d_in, const int* in_sizes, int n_in,
                              void* d_out, int out_size, void* d_ws, size_t ws_size,
                              hipStream_t stream){
  (void)in_sizes; (void)n_in; (void)out_size; (void)ws_size;
  const float* bb    = (const float*)d_in[0];
  const float* state = (const float*)d_in[1];
  const float* semt  = (const float*)d_in[2];
  const int*   mask  = (const int*)d_in[3];     // bool in ref; assumed int32 per harness ABI
  const float* obj   = (const float*)d_in[4];
  const float* inst  = (const float*)d_in[5];
  const float* W_in  = (const float*)d_in[6];
  const float* b_in  = (const float*)d_in[7];
  const float* uq    = (const float*)d_in[8];
  const float* ug    = (const float*)d_in[9];
  const float* ubv   = (const float*)d_in[10];
  const float* W1    = (const float*)d_in[11];
  const float* b1v   = (const float*)d_in[12];
  const float* W2    = (const float*)d_in[13];
  const float* b2v   = (const float*)d_in[14];
  const float* ng    = (const float*)d_in[15];
  const float* nbv   = (const float*)d_in[16];

  float* out = (float*)d_out;
  float* tf     = out;
  float* assign = out + ASG_OFF;
  float* uout   = out + UNI_OFF;

  char* ws = (char*)d_ws;
  f16*   wt_hi     = (f16*)(ws);                    // 1,105,920 B
  f16*   wt_lo     = (f16*)(ws + 1105920);          // 1,105,920 B
  float* units_cur = (float*)(ws + 2211840);        // 196,608 B
  float* upd_ws    = (float*)(ws + 2408448);        // 196,608 B
  float* denom_ws  = (float*)(ws + 2605056);        // 512 B

  k_prep<<<512, 256, 0, stream>>>(W_in, uq, wt_hi, wt_lo, units_cur);
  k_gemm<<<1536, 256, 0, stream>>>(bb, state, semt, obj, inst, wt_hi, wt_lo, b_in, tf);
  for (int it = 0; it < 3; ++it){
    k_zero<<<193, 256, 0, stream>>>(upd_ws, 49280);   // updates + denom (contiguous)
    const float* usrc = (it == 0) ? uq : units_cur;
    const int bs = (it == 0) ? 0 : (MUNITS*DDIM);
    k_assign<<<256, 256, 0, stream>>>(tf, usrc, bs, mask, assign, denom_ws);
    k_updates<<<256, 256, 0, stream>>>(tf, assign, upd_ws);
    k_units<<<128, 384, 0, stream>>>(upd_ws, denom_ws, usrc, bs,
                                     W1, b1v, W2, b2v, ug, ubv, ng, nbv,
                                     units_cur, (it == 2) ? uout : nullptr);
  }
}

// Round 3
// 908.442 us; speedup vs baseline: 1.2724x; 1.2724x over previous
//
#include <hip/hip_runtime.h>

// ---------------- problem constants ----------------
#define HID    1152
#define SEMD   256
#define STDD   8
#define DDIM   384
#define MUNITS 16
#define INDIM  1420
#define KPAD   1440     // 45*32, zero-padded
#define NSTEPS 45
#define BB     8
#define TT     64
#define KKT    128
#define NTOK   65536    // BB*TT*KKT
#define ASG_OFF  25165824   // NTOK*DDIM
#define UNI_OFF  26214400   // ASG_OFF + NTOK*MUNITS

typedef _Float16 f16;
typedef _Float16 f16x2 __attribute__((ext_vector_type(2)));
typedef _Float16 f16x4 __attribute__((ext_vector_type(4)));
typedef _Float16 f16x8 __attribute__((ext_vector_type(8)));
typedef float    f32x2 __attribute__((ext_vector_type(2)));
typedef float    f32x4 __attribute__((ext_vector_type(4)));
typedef unsigned int u32;

#define MFMA16(A,B,C) __builtin_amdgcn_mfma_f32_16x16x32_f16((A),(B),(C),0,0,0)

#define AS1 __attribute__((address_space(1)))
#define AS3 __attribute__((address_space(3)))
// async global->LDS DMA, 16B per lane; LDS dest = wave-uniform base + lane*16
__device__ __forceinline__ void dma16(const void* g, void* l){
  __builtin_amdgcn_global_load_lds((const AS1 u32*)g, (AS3 u32*)l, 16, 0, 0);
}

// fp32 -> f16 hi + scaled-lo split. lo scaled by 2^12 to stay in f16 normal
// range; cross-product accumulator scaled back by 2^-12 at epilogue.
// Residual ~2^-22 relative (below fp32 dot reorder noise).
__device__ __forceinline__ void fsplit(float v, f16 &h, f16 &l){
  f16 hh = (f16)v;
  h = hh;
  l = (f16)((v - (float)hh) * 4096.0f);
}

// ---------------- k_zero ----------------
__global__ void k_zero(float* __restrict__ p, int n){
  int i = blockIdx.x*256 + threadIdx.x;
  if (i < n) p[i] = 0.0f;
}

// ---------------- k_prep ----------------
// W_in transposed+split into fragment-friendly layout:
//   wt[(k>>3)*384*8 + n*8 + (k&7)]   (chunk-major; 16B per (chunk,col))
// unit_queries split into u_hi/u_lo fragment tables [b][chunk48][m16][8].
__global__ void k_prep(const float* __restrict__ W_in, const float* __restrict__ uq,
                       f16* __restrict__ wt_hi, f16* __restrict__ wt_lo,
                       f16* __restrict__ u_hi, f16* __restrict__ u_lo){
  const int tid = blockIdx.x*256 + threadIdx.x;
  const int nthr = gridDim.x*256;
  for (int i = tid; i < KPAD*DDIM; i += nthr){
    const int k = i / DDIM;
    const int n = i - k*DDIM;
    float v = (k < INDIM) ? W_in[i] : 0.0f;   // W_in row-major: i = k*384+n
    f16 h, l; fsplit(v, h, l);
    const int addr = (k>>3)*(DDIM*8) + n*8 + (k&7);
    wt_hi[addr] = h; wt_lo[addr] = l;
  }
  for (int i = tid; i < BB*MUNITS*DDIM; i += nthr){
    const int b = i / (MUNITS*DDIM);
    const int rem = i - b*(MUNITS*DDIM);
    const int m = rem / DDIM;
    const int d = rem - m*DDIM;
    f16 h, l; fsplit(uq[m*DDIM + d], h, l);
    const int off = ((b*48 + (d>>3))*MUNITS + m)*8 + (d&7);
    u_hi[off] = h; u_lo[off] = l;
  }
}

// ---------------- k_gemm ----------------
// tf = concat(backbone, sem, state, priors) @ W_in + b_in
// A: raw f32 staged to LDS via global_load_lds (pre-swizzled source so the
//    linear DMA dest yields an XOR-swizzled layout; reads conflict-free).
// B: hi/lo f16 fragments read directly from global (2.2MB, L2-resident).
// fp32 emulated: acc1 += Ah*Bh ; acc2 += Ah*Bl' + Al'*Bh (3 MFMA).
__global__ __launch_bounds__(256, 2)
void k_gemm(const float* __restrict__ bb, const float* __restrict__ state,
            const float* __restrict__ semt, const float* __restrict__ obj,
            const float* __restrict__ inst, const f16* __restrict__ wt_hi,
            const f16* __restrict__ wt_lo, const float* __restrict__ b_in,
            float* __restrict__ tf_out){
  __shared__ float As[2][128*32];   // [buf][row][slot*4]  slot = kq ^ (row&7)

  const int tid = threadIdx.x;
  const int lane = tid & 63;
  const int w = tid >> 6;
  const int bid = blockIdx.x;
  const int tokTile = bid / 3;
  const int nTile   = bid - tokTile*3;
  const int tok0 = tokTile*128;   // 128 tokens share (b,t); kk = row
  const int n0   = nTile*128;
  const int b    = tok0 >> 13;
  const int t    = (tok0 >> 7) & 63;
  const float tn = (float)t * (1.0f/63.0f);

  const int lrow = lane >> 3;              // row within 8-row DMA group
  const int kqs  = (lane & 7) ^ lrow;      // pre-swizzled source granule

  auto stageDMA = [&](int step, int bufsel){
    #pragma unroll
    for (int j = 0; j < 4; ++j){
      const int row = w*32 + j*8 + lrow;
      float* lp = &As[bufsel][(w*32 + j*8)*32];
      const float* gp;
      if (step < 36) gp = bb   + (size_t)(tok0+row)*HID  + step*32 + kqs*4;
      else           gp = semt + (size_t)(b*KKT+row)*SEMD + (step-36)*32 + kqs*4;
      dma16(gp, lp);
    }
  };
  auto stage44 = [&](int bufsel){          // k 1408..1439: state|obj|inst|tn|1-tn|pad
    const int row = tid >> 1;
    const int half = tid & 1;
    float* dst = &As[bufsel][row*32];
    const int r7 = row & 7;
    if (half == 0){
      const f32x4 s0 = *(const f32x4*)(state + (size_t)(tok0+row)*STDD);
      const f32x4 s1 = *(const f32x4*)(state + (size_t)(tok0+row)*STDD + 4);
      float pv[8];
      pv[0] = obj[b*KKT + row];
      pv[1] = inst[(size_t)(b*KKT + row)*TT + t];
      pv[2] = tn; pv[3] = 1.0f - tn;
      pv[4] = 0.f; pv[5] = 0.f; pv[6] = 0.f; pv[7] = 0.f;
      #pragma unroll
      for (int c = 0; c < 16; ++c){
        const float v = (c < 4) ? s0[c] : (c < 8) ? s1[c-4] : pv[c-8];
        dst[((c>>2) ^ r7)*4 + (c&3)] = v;
      }
    } else {
      #pragma unroll
      for (int c = 16; c < 32; ++c){
        dst[((c>>2) ^ r7)*4 + (c&3)] = 0.0f;
      }
    }
  };

  const int r16 = lane & 15;
  const int kc  = lane >> 4;
  const int wm  = (w >> 1)*64;
  const int wn  = (w & 1)*64;

  f32x4 acc1[4][4], acc2[4][4];
  #pragma unroll
  for (int m=0;m<4;++m){
    #pragma unroll
    for (int n=0;n<4;++n){
      f32x4 z = {0.f,0.f,0.f,0.f};
      acc1[m][n] = z; acc2[m][n] = z;
    }
  }

  const f16* bhbase = wt_hi + (size_t)(n0 + wn + r16)*8;
  const f16* blbase = wt_lo + (size_t)(n0 + wn + r16)*8;

  stageDMA(0, 0);
  __syncthreads();

  for (int step = 0; step < NSTEPS; ++step){
    const int buf = step & 1;
    if (step < 43)       stageDMA(step+1, buf^1);
    else if (step == 43) stage44(buf^1);

    f16x8 bhv[4], blv[4];
    const size_t chunkoff = (size_t)(step*4 + kc)*(DDIM*8);
    #pragma unroll
    for (int n = 0; n < 4; ++n){
      bhv[n] = *(const f16x8*)(bhbase + chunkoff + n*(16*8));
      blv[n] = *(const f16x8*)(blbase + chunkoff + n*(16*8));
    }

    const float* Ab = As[buf];
    #pragma unroll
    for (int m = 0; m < 4; ++m){
      const int row = wm + m*16 + r16;
      const int r7 = row & 7;
      f16x8 ah, al;
      #pragma unroll
      for (int gi = 0; gi < 2; ++gi){
        const int slot = (kc*2 + gi) ^ r7;
        const f32x4 x = *(const f32x4*)&Ab[row*32 + slot*4];
        #pragma unroll
        for (int jj = 0; jj < 4; ++jj){
          f16 hh, ll; fsplit(x[jj], hh, ll);
          ah[gi*4+jj] = hh; al[gi*4+jj] = ll;
        }
      }
      #pragma unroll
      for (int n = 0; n < 4; ++n){
        acc1[m][n] = MFMA16(ah, bhv[n], acc1[m][n]);
        acc2[m][n] = MFMA16(ah, blv[n], acc2[m][n]);
        acc2[m][n] = MFMA16(al, bhv[n], acc2[m][n]);
      }
    }
    __syncthreads();
  }

  #pragma unroll
  for (int n=0;n<4;++n){
    const int col = n0 + wn + n*16 + r16;
    const float bias = b_in[col];
    #pragma unroll
    for (int m=0;m<4;++m){
      #pragma unroll
      for (int j=0;j<4;++j){
        const int row = tok0 + wm + m*16 + kc*4 + j;   // C: row=(lane>>4)*4+reg
        tf_out[(size_t)row*DDIM + col] = acc1[m][n][j] + acc2[m][n][j]*(1.0f/4096.0f) + bias;
      }
    }
  }
}

// ---------------- k_assign ----------------
// logits = tf @ units^T * scale (bias is constant across m: cancels in both
// top-k and softmax). Units read as pre-split global fragment tables (L2-hot,
// no LDS, no barriers). 32 tokens per wave, per-wave denom partials.
__global__ __launch_bounds__(256)
void k_assign(const float* __restrict__ tf, const f16* __restrict__ u_hi,
              const f16* __restrict__ u_lo, const int* __restrict__ mask,
              float* __restrict__ asg, float* __restrict__ partial){
  const int tid = threadIdx.x;
  const int lane = tid & 63;
  const int w = tid >> 6;
  const int gw = blockIdx.x*4 + w;     // 0..2047
  const int tw = gw*32;
  const int b = gw >> 8;
  const int r16 = lane & 15;
  const int kc  = lane >> 4;
  const int maskbase = b*KKT;
  float dsum = 0.0f;

  #pragma unroll 1
  for (int mf = 0; mf < 2; ++mf){
    f32x4 l1 = {0.f,0.f,0.f,0.f};
    f32x4 l2 = {0.f,0.f,0.f,0.f};
    const float* tfrow = tf + (size_t)(tw + mf*16 + r16)*DDIM + kc*8;
    #pragma unroll
    for (int step = 0; step < 12; ++step){
      const f32x4 x0 = *(const f32x4*)(tfrow + step*32);
      const f32x4 x1 = *(const f32x4*)(tfrow + step*32 + 4);
      f16x8 ah, al;
      #pragma unroll
      for (int j=0;j<4;++j){ f16 hh,ll; fsplit(x0[j],hh,ll); ah[j]=hh;   al[j]=ll; }
      #pragma unroll
      for (int j=0;j<4;++j){ f16 hh,ll; fsplit(x1[j],hh,ll); ah[4+j]=hh; al[4+j]=ll; }
      const int uoff = ((b*48 + step*4 + kc)*MUNITS + r16)*8;
      const f16x8 bh = *(const f16x8*)(u_hi + uoff);
      const f16x8 bl = *(const f16x8*)(u_lo + uoff);
      l1 = MFMA16(ah, bh, l1);
      l2 = MFMA16(ah, bl, l2);
      l2 = MFMA16(al, bh, l2);
    }
    #pragma unroll
    for (int j = 0; j < 4; ++j){
      const float v = (l1[j] + l2[j]*(1.0f/4096.0f)) * 0.051031036307982876f; // 1/sqrt(384)
      const int tokr = tw + mf*16 + kc*4 + j;
      // top-1 over the 16 lanes (m dim), ties -> lower index
      float vmax = v; int imax = r16;
      #pragma unroll
      for (int s=1;s<16;s<<=1){
        const float ov = __shfl_xor(vmax, s, 16);
        const int   oi = __shfl_xor(imax, s, 16);
        if (ov > vmax || (ov == vmax && oi < imax)){ vmax = ov; imax = oi; }
      }
      // top-2 (exclude imax)
      float v2 = (r16 == imax) ? -3.0e38f : v;
      int   i2 = (r16 == imax) ? 127 : r16;
      #pragma unroll
      for (int s=1;s<16;s<<=1){
        const float ov = __shfl_xor(v2, s, 16);
        const int   oi = __shfl_xor(i2, s, 16);
        if (ov > v2 || (ov == v2 && oi < i2)){ v2 = ov; i2 = oi; }
      }
      const float e = expf((v2 - vmax) / 0.7f);
      const float a1 = 1.0f/(1.0f + e);
      const float a2 = e/(1.0f + e);
      const bool valid = mask[maskbase + (tokr & 127)] != 0;
      float myv = 0.0f;
      if (valid){
        if (r16 == imax) myv = a1;
        else if (r16 == i2) myv = a2;
      }
      asg[(size_t)tokr*MUNITS + r16] = myv;
      dsum += myv;
    }
  }
  // reduce across the 4 kc groups; lanes 0..15 then hold per-m wave sums
  dsum += __shfl_xor(dsum, 16, 64);
  dsum += __shfl_xor(dsum, 32, 64);
  if (lane < 16) partial[(size_t)(b*MUNITS + r16)*256 + (gw & 255)] = dsum;
}

// ---------------- k_updates ----------------
// updates[b][m][d] = sum_tok assignment[tok][m] * tf[tok][d]
// A = assignment^T (M=16), B = tf via LDS transpose, f16-split x3.
__global__ void k_updates(const float* __restrict__ tf, const float* __restrict__ asg,
                          float* __restrict__ upd_ws){
  __shared__ f16 Bt_hi[DDIM*40];   // [d][tok(32) + pad8]
  __shared__ f16 Bt_lo[DDIM*40];
  __shared__ f16 At_hi[512];       // [c(4)][m(16)][8]
  __shared__ f16 At_lo[512];

  const int tid = threadIdx.x;
  const int b = blockIdx.x >> 6;
  const int chunk = blockIdx.x & 63;
  const int tokB = b*8192 + chunk*128;

  const int lane = tid & 63;
  const int w = tid >> 6;
  const int r16 = lane & 15;
  const int kc = lane >> 4;
  const int dbase = w*96;

  const int p = tid & 15;          // token pair
  const int dseg = tid >> 4;       // 16 segs x 24 d

  f32x4 acc1[6], acc2[6];
  #pragma unroll
  for (int n=0;n<6;++n){ f32x4 z={0.f,0.f,0.f,0.f}; acc1[n]=z; acc2[n]=z; }

  for (int step = 0; step < 4; ++step){
    const int tok0s = tokB + step*32;
    { // stage tf -> Bt (transpose + split)
      const size_t r0 = (size_t)(tok0s + 2*p)*DDIM;
      const size_t r1 = r0 + DDIM;
      #pragma unroll
      for (int q = 0; q < 6; ++q){
        const f32x4 xa = *(const f32x4*)(tf + r0 + dseg*24 + q*4);
        const f32x4 xb = *(const f32x4*)(tf + r1 + dseg*24 + q*4);
        #pragma unroll
        for (int j = 0; j < 4; ++j){
          const int d = dseg*24 + q*4 + j;
          f16 ha, la, hb, lb;
          fsplit(xa[j], ha, la);
          fsplit(xb[j], hb, lb);
          f16x2 hh = {ha, hb};
          f16x2 ll = {la, lb};
          *(f16x2*)&Bt_hi[d*40 + 2*p] = hh;
          *(f16x2*)&Bt_lo[d*40 + 2*p] = ll;
        }
      }
    }
    { // stage assignment -> At (transpose + split)
      const int idx = tid*2;
      const int tokr = idx >> 4;
      const int m2 = idx & 15;
      const f32x2 av = *(const f32x2*)(asg + (size_t)(tok0s + tokr)*MUNITS + m2);
      #pragma unroll
      for (int j = 0; j < 2; ++j){
        f16 h, l; fsplit(av[j], h, l);
        const int off = ((tokr>>3)*16 + m2 + j)*8 + (tokr&7);
        At_hi[off] = h; At_lo[off] = l;
      }
    }
    __syncthreads();
    const f16x8 ah = *(const f16x8*)&At_hi[(kc*16 + r16)*8];
    const f16x8 al = *(const f16x8*)&At_lo[(kc*16 + r16)*8];
    #pragma unroll
    for (int n = 0; n < 6; ++n){
      const int d = dbase + n*16 + r16;
      const f16x8 bh = *(const f16x8*)&Bt_hi[d*40 + kc*8];
      const f16x8 bl = *(const f16x8*)&Bt_lo[d*40 + kc*8];
      acc1[n] = MFMA16(ah, bh, acc1[n]);
      acc2[n] = MFMA16(ah, bl, acc2[n]);
      acc2[n] = MFMA16(al, bh, acc2[n]);
    }
    __syncthreads();
  }

  #pragma unroll
  for (int n = 0; n < 6; ++n){
    #pragma unroll
    for (int j = 0; j < 4; ++j){
      const int m = kc*4 + j;
      const int d = dbase + n*16 + r16;
      atomicAdd(&upd_ws[(size_t)(b*MUNITS + m)*DDIM + d],
                acc1[n][j] + acc2[n][j]*(1.0f/4096.0f));
    }
  }
}

// ---------------- k_units ----------------
// One block (384 threads) per (b,m): reduce denom partials, updates/denom ->
// LN -> GELU-MLP -> residual LN; writes next-iter split unit tables.
__global__ void k_units(const float* __restrict__ upd_ws, const float* __restrict__ partial,
                        const float* __restrict__ units_in, int bstride,
                        const float* __restrict__ W1, const float* __restrict__ b1v,
                        const float* __restrict__ W2, const float* __restrict__ b2v,
                        const float* __restrict__ ug, const float* __restrict__ ubv,
                        const float* __restrict__ ng, const float* __restrict__ nbv,
                        float* __restrict__ units_out,
                        f16* __restrict__ u_hi, f16* __restrict__ u_lo,
                        float* __restrict__ final_out){
  const int bm = blockIdx.x;
  const int bq = bm >> 4, mq = bm & 15;
  const int tid = threadIdx.x;    // 384
  __shared__ float uln[DDIM];
  __shared__ float gact[2*DDIM];
  __shared__ float red[8];
  __shared__ float dnm_sh;

  { // denom = sum of 256 per-wave partials
    float pv = (tid < 256) ? partial[(size_t)bm*256 + tid] : 0.0f;
    #pragma unroll
    for (int sh=1; sh<64; sh<<=1) pv += __shfl_xor(pv, sh, 64);
    if ((tid & 63) == 0 && tid < 256) red[4 + (tid>>6)] = pv;
    __syncthreads();
    if (tid == 0){
      float dn = red[4]+red[5]+red[6]+red[7];
      dnm_sh = (dn < 1e-6f) ? 1e-6f : dn;
    }
    __syncthreads();
  }

  float u = upd_ws[(size_t)bm*DDIM + tid] / dnm_sh;

  float s = u;
  #pragma unroll
  for (int sh=1; sh<64; sh<<=1) s += __shfl_xor(s, sh, 64);
  if ((tid&63)==0) red[tid>>6] = s;
  __syncthreads();
  const float mu = (red[0]+red[1]+red[2]+red[3]+red[4]+red[5]) * (1.0f/384.0f);
  __syncthreads();
  const float d = u - mu;
  float s2 = d*d;
  #pragma unroll
  for (int sh=1; sh<64; sh<<=1) s2 += __shfl_xor(s2, sh, 64);
  if ((tid&63)==0) red[tid>>6] = s2;
  __syncthreads();
  const float var = (red[0]+red[1]+red[2]+red[3]+red[4]+red[5]) * (1.0f/384.0f);
  const float rs = rsqrtf(var + 1e-5f);
  uln[tid] = d * rs * ug[tid] + ubv[tid];
  __syncthreads();

  { // h1 = uln @ W1 + b1 ; exact GELU
    float a0 = 0.f, a1 = 0.f;
    for (int dd = 0; dd < DDIM; ++dd){
      const float x = uln[dd];
      a0 += x * W1[(size_t)dd*768 + tid];
      a1 += x * W1[(size_t)dd*768 + tid + 384];
    }
    a0 += b1v[tid]; a1 += b1v[tid + 384];
    gact[tid]     = 0.5f*a0*(1.0f + erff(a0*0.70710678118654752f));
    gact[tid+384] = 0.5f*a1*(1.0f + erff(a1*0.70710678118654752f));
  }
  __syncthreads();

  float h2 = 0.f;
  for (int dd = 0; dd < 2*DDIM; ++dd){
    h2 += gact[dd] * W2[(size_t)dd*DDIM + tid];
  }
  h2 += b2v[tid];
  const float r = units_in[(size_t)bq*bstride + mq*DDIM + tid] + h2;

  float sr = r;
  #pragma unroll
  for (int sh=1; sh<64; sh<<=1) sr += __shfl_xor(sr, sh, 64);
  if ((tid&63)==0) red[tid>>6] = sr;
  __syncthreads();
  const float mu2 = (red[0]+red[1]+red[2]+red[3]+red[4]+red[5]) * (1.0f/384.0f);
  __syncthreads();
  const float d2 = r - mu2;
  float sq2 = d2*d2;
  #pragma unroll
  for (int sh=1; sh<64; sh<<=1) sq2 += __shfl_xor(sq2, sh, 64);
  if ((tid&63)==0) red[tid>>6] = sq2;
  __syncthreads();
  const float var2 = (red[0]+red[1]+red[2]+red[3]+red[4]+red[5]) * (1.0f/384.0f);
  const float rs2 = rsqrtf(var2 + 1e-5f);
  const float outv = d2 * rs2 * ng[tid] + nbv[tid];
  units_out[(size_t)bm*DDIM + tid] = outv;

  { // split for next iteration's k_assign fragment reads
    f16 oh, ol; fsplit(outv, oh, ol);
    const int uoff = ((bq*48 + (tid>>3))*MUNITS + mq)*8 + (tid&7);
    u_hi[uoff] = oh; u_lo[uoff] = ol;
  }
  if (final_out) final_out[(size_t)bm*DDIM + tid] = outv;
}

// ---------------- launch ----------------
extern "C" void kernel_launch(void* const* d_in, const int* in_sizes, int n_in,
                              void* d_out, int out_size, void* d_ws, size_t ws_size,
                              hipStream_t stream){
  (void)in_sizes; (void)n_in; (void)out_size; (void)ws_size;
  const float* bb    = (const float*)d_in[0];
  const float* state = (const float*)d_in[1];
  const float* semt  = (const float*)d_in[2];
  const int*   mask  = (const int*)d_in[3];
  const float* obj   = (const float*)d_in[4];
  const float* inst  = (const float*)d_in[5];
  const float* W_in  = (const float*)d_in[6];
  const float* b_in  = (const float*)d_in[7];
  const float* uq    = (const float*)d_in[8];
  const float* ug    = (const float*)d_in[9];
  const float* ubv   = (const float*)d_in[10];
  const float* W1    = (const float*)d_in[11];
  const float* b1v   = (const float*)d_in[12];
  const float* W2    = (const float*)d_in[13];
  const float* b2v   = (const float*)d_in[14];
  const float* ng    = (const float*)d_in[15];
  const float* nbv   = (const float*)d_in[16];

  float* out = (float*)d_out;
  float* tf     = out;
  float* assign = out + ASG_OFF;
  float* uout   = out + UNI_OFF;

  char* ws = (char*)d_ws;
  f16*   wt_hi     = (f16*)(ws);                    // 1,105,920 B
  f16*   wt_lo     = (f16*)(ws + 1105920);          // 1,105,920 B
  float* units_cur = (float*)(ws + 2211840);        // 196,608 B
  float* upd_ws    = (float*)(ws + 2408448);        // 196,608 B
  f16*   u_hi      = (f16*)(ws + 2605056);          // 98,304 B
  f16*   u_lo      = (f16*)(ws + 2703360);          // 98,304 B
  float* partial   = (float*)(ws + 2801664);        // 131,072 B

  k_prep<<<512, 256, 0, stream>>>(W_in, uq, wt_hi, wt_lo, u_hi, u_lo);
  k_gemm<<<1536, 256, 0, stream>>>(bb, state, semt, obj, inst, wt_hi, wt_lo, b_in, tf);
  for (int it = 0; it < 3; ++it){
    k_zero<<<192, 256, 0, stream>>>(upd_ws, 49152);
    k_assign<<<512, 256, 0, stream>>>(tf, u_hi, u_lo, mask, assign, partial);
    k_updates<<<512, 256, 0, stream>>>(tf, assign, upd_ws);
    const float* usrc = (it == 0) ? uq : units_cur;
    const int bs = (it == 0) ? 0 : (MUNITS*DDIM);
    k_units<<<128, 384, 0, stream>>>(upd_ws, partial, usrc, bs,
                                     W1, b1v, W2, b2v, ug, ubv, ng, nbv,
                                     units_cur, u_hi, u_lo,
                                     (it == 2) ? uout : nullptr);
  }
}